// Round 5
// baseline (413.574 us; speedup 1.0000x reference)
//
#include <hip/hip_runtime.h>
#include <math.h>

// Problem constants
#define NB   4
#define SEQ  1024
#define DMOD 512
#define NHD  8
#define DK   64

typedef unsigned short ushort_t;
typedef __attribute__((ext_vector_type(8))) short bf16x8;
typedef __attribute__((ext_vector_type(4))) float f32x4;

// ---------------- workspace layout (bytes) ----------------
#define XQ_OFF   1024
#define XK_OFF   (XQ_OFF + 4194304)
#define XV_OFF   (XK_OFF + 4194304)
#define WQ_OFF   (XV_OFF + 4194304)
#define WK_OFF   (WQ_OFF + 524288)
#define WV_OFF   (WK_OFF + 524288)
#define WF_OFF   (WV_OFF + 524288)
#define QBF_OFF  (WF_OFF + 524288)
#define KBF_OFF  (QBF_OFF + 4194304)
#define VT_OFF   (KBF_OFF + 12582912)
// aliases (stream-ordered safe):
#define O2_OFF   XQ_OFF   // fp32 8MB, written by fc AFTER fused_attn
#define OBF_OFF  XV_OFF   // bf16 4MB, written by fused attn after XV dead
#define POSBF_OFF XQ_OFF  // 4MB packed-bf16 pos; written after gemm<0> (XQ dead),
                          // read by fused_attn, overwritten by O2 afterwards.

__device__ inline ushort_t f2bf(float x) {
    unsigned u = __builtin_bit_cast(unsigned, x);
    unsigned r = (u + 0x7FFFu + ((u >> 16) & 1u)) >> 16;
    return (ushort_t)r;
}
__device__ inline unsigned pk2(float a, float b) {
    return (unsigned)f2bf(a) | ((unsigned)f2bf(b) << 16);
}

__global__ __launch_bounds__(64)
void prep_kernel(const float* __restrict__ rp_w1, const float* __restrict__ rp_b1,
                 const float* __restrict__ rp_w2, const float* __restrict__ rp_b2,
                 float* __restrict__ ws)
{
    int d = threadIdx.x;
    float w0 = 0.f, w1 = 0.f, cc = 0.f;
    for (int j = 0; j < 64; j++) {
        float r2 = rp_w2[d * 64 + j];
        w0 += r2 * rp_w1[j * 2 + 0];
        w1 += r2 * rp_w1[j * 2 + 1];
        cc += r2 * rp_b1[j];
    }
    ws[d] = cc + rp_b2[d];
    ws[64 + 2 * d + 0] = w0;
    ws[64 + 2 * d + 1] = w1;
}

__global__ __launch_bounds__(256)
void cvt3_kernel(const float* __restrict__ s0, const float* __restrict__ s1,
                 const float* __restrict__ s2, ushort_t* __restrict__ d0,
                 ushort_t* __restrict__ d1, ushort_t* __restrict__ d2)
{
    int t = blockIdx.x * 256 + threadIdx.x;
    const float* s = (blockIdx.y == 0) ? s0 : (blockIdx.y == 1) ? s1 : s2;
    ushort_t* d = (blockIdx.y == 0) ? d0 : (blockIdx.y == 1) ? d1 : d2;
    float4 v = *(const float4*)&s[t * 4];
    uint2 o = {pk2(v.x, v.y), pk2(v.z, v.w)};
    *(uint2*)&d[t * 4] = o;
}

__global__ __launch_bounds__(256)
void cvt4_kernel(const float* __restrict__ s0, const float* __restrict__ s1,
                 const float* __restrict__ s2, const float* __restrict__ s3,
                 ushort_t* __restrict__ d0, ushort_t* __restrict__ d1,
                 ushort_t* __restrict__ d2, ushort_t* __restrict__ d3)
{
    int t = blockIdx.x * 256 + threadIdx.x;
    const float* s = (blockIdx.y == 0) ? s0 : (blockIdx.y == 1) ? s1
                   : (blockIdx.y == 2) ? s2 : s3;
    ushort_t* d = (blockIdx.y == 0) ? d0 : (blockIdx.y == 1) ? d1
                : (blockIdx.y == 2) ? d2 : d3;
    float4 v = *(const float4*)&s[t * 4];
    uint2 o = {pk2(v.x, v.y), pk2(v.z, v.w)};
    *(uint2*)&d[t * 4] = o;
}

// pos (S,S,2) fp32 -> packed bf16 pair per (q,k): u = bf16(ch0) | bf16(ch1)<<16
__global__ __launch_bounds__(256)
void poscvt_kernel(const float* __restrict__ pos, unsigned* __restrict__ posbf)
{
    int t = blockIdx.x * 256 + threadIdx.x;     // 262144 threads, 4 pairs each
    float4 a = *(const float4*)&pos[t * 8];
    float4 b = *(const float4*)&pos[t * 8 + 4];
    uint4 o = {pk2(a.x, a.y), pk2(a.z, a.w), pk2(b.x, b.y), pk2(b.z, b.w)};
    *(uint4*)&posbf[t * 4] = o;
}

// MFMA NT GEMM: Y[n,o] = sum_m X[n,m]*Wt[o,m]; N=4096, O=512, M=512, bf16 in.
#define GP 72
template<int MODE>
__global__ __launch_bounds__(256)
void mfma_gemm(const ushort_t* __restrict__ X, const ushort_t* __restrict__ Wt,
               ushort_t* __restrict__ obf, float* __restrict__ ofp,
               const float* __restrict__ wc, const float* __restrict__ resid)
{
    __shared__ ushort_t Xs[64 * GP];
    __shared__ ushort_t Ws[64 * GP];
    const int n0 = blockIdx.y * 64;
    const int o0 = blockIdx.x * 64;
    const int tid = threadIdx.x;
    const int wave = tid >> 6, lane = tid & 63;
    const int m16 = lane & 15, g = lane >> 4;

    f32x4 acc[4] = {};
    for (int m0 = 0; m0 < 512; m0 += 64) {
        #pragma unroll
        for (int it = 0; it < 2; it++) {
            int idx = tid + it * 256;
            int row = idx >> 3, c8 = (idx & 7) * 8;
            *(uint4*)&Xs[row * GP + c8] = *(const uint4*)&X[(n0 + row) * 512 + m0 + c8];
            *(uint4*)&Ws[row * GP + c8] = *(const uint4*)&Wt[(o0 + row) * 512 + m0 + c8];
        }
        __syncthreads();
        #pragma unroll
        for (int kc = 0; kc < 2; kc++) {
            bf16x8 a = *(const bf16x8*)&Xs[(wave * 16 + m16) * GP + kc * 32 + g * 8];
            #pragma unroll
            for (int to = 0; to < 4; to++) {
                bf16x8 b = *(const bf16x8*)&Ws[(to * 16 + m16) * GP + kc * 32 + g * 8];
                acc[to] = __builtin_amdgcn_mfma_f32_16x16x32_bf16(a, b, acc[to], 0, 0, 0);
            }
        }
        __syncthreads();
    }
    #pragma unroll
    for (int to = 0; to < 4; to++) {
        int o = o0 + to * 16 + m16;
        #pragma unroll
        for (int r = 0; r < 4; r++) {
            int n = n0 + wave * 16 + g * 4 + r;
            float a = acc[to][r];
            int b = n >> 10, s = n & 1023, h = o >> 6, d = o & 63;
            if (MODE == 0) {
                obf[(((b * NHD + h) << 10) + s) * 64 + d] = f2bf(a);
            } else if (MODE == 1) {
                int base = ((((b * NHD + h) << 10) + s) * 192) + d;
                obf[base]       = f2bf(a * wc[d]);
                obf[base + 64]  = f2bf(a * wc[64 + 2 * d + 0]);
                obf[base + 128] = f2bf(a * wc[64 + 2 * d + 1]);
            } else if (MODE == 2) {
                obf[((b * NHD + h) * 64 + d) * 1024 + s] = f2bf(a);
            } else {
                ofp[n * 512 + o] = a + resid[n * 512 + o];
            }
        }
    }
}

// ---------------------------------------------------------------------------
// Fused score + softmax + PV (flash-style, two-pass, static-max softmax).
// R4 change (T14 async-STAGE split): in R3 the staging global loads were
// issued AFTER the previous tile's end-barrier, so their full ~500cy latency
// sat exposed between barriers with only 2 waves/SIMD to cover it (counters:
// MfmaUtil 13.7 + VALUBusy 35.6 => ~50% of cycles idle). Now each tile's
// K/pos(/V) global loads are issued into REGISTERS at the top of the previous
// tile's compute (QK MFMA + exp + PV hide the latency), and the reg->LDS
// write happens after the barrier that retires the previous tile's LDS reads.
// Barrier count per tile unchanged (2 in pass 1, 3 in pass 2). +48 VGPR.
// ---------------------------------------------------------------------------
#define QPITCH 72
#define KPLANE (64 * QPITCH + 8)
#define POSP 68   // uints per pos row: 64 + 4 pad (row pitch 272B, 16B-aligned)
__global__ __launch_bounds__(256)
void fused_attn(const ushort_t* __restrict__ Qbf, const ushort_t* __restrict__ Kbf,
                const unsigned* __restrict__ posu, const ushort_t* __restrict__ Vt,
                float* __restrict__ attn, ushort_t* __restrict__ Obf)
{
    __shared__ ushort_t Ks[3 * KPLANE];      // 27696 B
    __shared__ ushort_t Vs[64 * QPITCH];     //  9216 B
    __shared__ ushort_t Ps[64 * QPITCH];     //  9216 B
    __shared__ unsigned PosS[64 * POSP];     // 17408 B   (total 63536 B)
    const int bh = blockIdx.x;
    const int q0 = blockIdx.y * 64;
    const int tid = threadIdx.x;
    const int wave = tid >> 6, lane = tid & 63;
    const int m16 = lane & 15, g = lane >> 4;

    // staging address components (constant per thread)
    const int k_row = (tid % 192) / 24 + (tid / 192) * 8;   // unused; keep simple below
    (void)k_row;

    // Q fragment directly global -> registers (one-time, 16B x2 per thread)
    const ushort_t* qrow = &Qbf[((bh << 10) + q0 + wave * 16 + m16) * 64];
    bf16x8 qf0 = *(const bf16x8*)&qrow[g * 8];
    bf16x8 qf1 = *(const bf16x8*)&qrow[32 + g * 8];

    uint4 kreg[6], preg[4], vreg[2];

    // ---- staging helpers (index math kept identical to R3) ----
#define LOAD_K(k0_) \
    _Pragma("unroll") \
    for (int it = 0; it < 6; it++) { \
        int idx = tid + it * 256; \
        int row = idx / 24, c = idx % 24; \
        kreg[it] = *(const uint4*)&Kbf[((bh << 10) + (k0_) + row) * 192 + c * 8]; \
    }
#define LOAD_P(k0_) \
    _Pragma("unroll") \
    for (int it = 0; it < 4; it++) { \
        int idx = tid + it * 256; \
        int row = idx >> 4, c4 = (idx & 15) * 4; \
        preg[it] = *(const uint4*)&posu[(q0 + row) * 1024 + (k0_) + c4]; \
    }
#define LOAD_V(k0_) \
    _Pragma("unroll") \
    for (int it = 0; it < 2; it++) { \
        int idx = tid + it * 256; \
        int row = idx >> 3, c8 = (idx & 7) * 8; \
        vreg[it] = *(const uint4*)&Vt[(bh * 64 + row) * 1024 + (k0_) + c8]; \
    }
#define STORE_K() \
    _Pragma("unroll") \
    for (int it = 0; it < 6; it++) { \
        int idx = tid + it * 256; \
        int row = idx / 24, c = idx % 24; \
        int j = c >> 3, d8 = (c & 7) * 8; \
        *(uint4*)&Ks[j * KPLANE + row * QPITCH + d8] = kreg[it]; \
    }
#define STORE_P() \
    _Pragma("unroll") \
    for (int it = 0; it < 4; it++) { \
        int idx = tid + it * 256; \
        int row = idx >> 4, c4 = (idx & 15) * 4; \
        *(uint4*)&PosS[row * POSP + c4] = preg[it]; \
    }
#define STORE_V() \
    _Pragma("unroll") \
    for (int it = 0; it < 2; it++) { \
        int idx = tid + it * 256; \
        int row = idx >> 3, c8 = (idx & 7) * 8; \
        *(uint4*)&Vs[row * QPITCH + c8] = vreg[it]; \
    }

    float l[4] = {0.f, 0.f, 0.f, 0.f};

    // ---------------- pass 1: denominator sum (static max = 0) ----------------
    LOAD_K(0); LOAD_P(0);
    STORE_K(); STORE_P();
    __syncthreads();
    for (int k0 = 0; k0 < 1024; k0 += 64) {
        const int kn = k0 + 64;
        if (kn < 1024) {            // issue next tile's global loads early
            LOAD_K(kn); LOAD_P(kn);
        }

        f32x4 sc[4][3] = {};
        #pragma unroll
        for (int kc = 0; kc < 2; kc++) {
            bf16x8 af = kc ? qf1 : qf0;
            #pragma unroll
            for (int tk = 0; tk < 4; tk++)
                #pragma unroll
                for (int j = 0; j < 3; j++) {
                    bf16x8 bfv = *(const bf16x8*)&Ks[j * KPLANE + (tk * 16 + m16) * QPITCH + kc * 32 + g * 8];
                    sc[tk][j] = __builtin_amdgcn_mfma_f32_16x16x32_bf16(af, bfv, sc[tk][j], 0, 0, 0);
                }
        }

        #pragma unroll
        for (int r = 0; r < 4; r++) {
            #pragma unroll
            for (int tk = 0; tk < 4; tk++) {
                unsigned pu = PosS[(wave * 16 + g * 4 + r) * POSP + tk * 16 + m16];
                float p0 = __builtin_bit_cast(float, pu << 16);
                float p1 = __builtin_bit_cast(float, pu & 0xFFFF0000u);
                float s = (sc[tk][0][r] + p0 * sc[tk][1][r] + p1 * sc[tk][2][r]) * 0.125f;
                l[r] += __expf(s);
            }
        }
        __syncthreads();            // tile k0's LDS reads retired
        if (kn < 1024) {
            STORE_K(); STORE_P();   // regs (already landed under compute) -> LDS
        }
        __syncthreads();
    }
    // single cross-lane reduce (16-lane groups share the same q rows)
    float inv_l[4];
    #pragma unroll
    for (int r = 0; r < 4; r++) {
        float s = l[r];
        #pragma unroll
        for (int msk = 1; msk < 16; msk <<= 1) s += __shfl_xor(s, msk, 64);
        inv_l[r] = 1.0f / s;
    }
    __syncthreads();

    // ---------------- pass 2: probs write + PV ----------------
    f32x4 ao[4] = {};
    LOAD_K(0); LOAD_P(0); LOAD_V(0);
    STORE_K(); STORE_P(); STORE_V();
    __syncthreads();
    for (int k0 = 0; k0 < 1024; k0 += 64) {
        const int kn = k0 + 64;
        if (kn < 1024) {            // issue next tile's global loads early
            LOAD_K(kn); LOAD_P(kn); LOAD_V(kn);
        }

        f32x4 sc[4][3] = {};
        #pragma unroll
        for (int kc = 0; kc < 2; kc++) {
            bf16x8 af = kc ? qf1 : qf0;
            #pragma unroll
            for (int tk = 0; tk < 4; tk++)
                #pragma unroll
                for (int j = 0; j < 3; j++) {
                    bf16x8 bfv = *(const bf16x8*)&Ks[j * KPLANE + (tk * 16 + m16) * QPITCH + kc * 32 + g * 8];
                    sc[tk][j] = __builtin_amdgcn_mfma_f32_16x16x32_bf16(af, bfv, sc[tk][j], 0, 0, 0);
                }
        }

        #pragma unroll
        for (int r = 0; r < 4; r++) {
            int q = q0 + wave * 16 + g * 4 + r;
            #pragma unroll
            for (int tk = 0; tk < 4; tk++) {
                unsigned pu = PosS[(wave * 16 + g * 4 + r) * POSP + tk * 16 + m16];
                float p0 = __builtin_bit_cast(float, pu << 16);
                float p1 = __builtin_bit_cast(float, pu & 0xFFFF0000u);
                float s = (sc[tk][0][r] + p0 * sc[tk][1][r] + p1 * sc[tk][2][r]) * 0.125f;
                float p = __expf(s) * inv_l[r];
                attn[((bh << 10) + q) * 1024 + k0 + tk * 16 + m16] = p;
                Ps[(wave * 16 + g * 4 + r) * QPITCH + tk * 16 + m16] = f2bf(p);
            }
        }
        __syncthreads();            // Ps visible; PosS/Ks reads retired

        #pragma unroll
        for (int kc = 0; kc < 2; kc++) {
            bf16x8 a = *(const bf16x8*)&Ps[(wave * 16 + m16) * QPITCH + kc * 32 + g * 8];
            #pragma unroll
            for (int td = 0; td < 4; td++) {
                bf16x8 b = *(const bf16x8*)&Vs[(td * 16 + m16) * QPITCH + kc * 32 + g * 8];
                ao[td] = __builtin_amdgcn_mfma_f32_16x16x32_bf16(a, b, ao[td], 0, 0, 0);
            }
        }
        __syncthreads();            // Vs/Ps reads retired
        if (kn < 1024) {
            STORE_K(); STORE_P(); STORE_V();
        }
        __syncthreads();
    }

    const int b = bh >> 3, h = bh & 7;
    #pragma unroll
    for (int td = 0; td < 4; td++) {
        int d = td * 16 + m16;
        #pragma unroll
        for (int r = 0; r < 4; r++) {
            int q = q0 + wave * 16 + g * 4 + r;
            Obf[((b << 10) + q) * 512 + h * 64 + d] = f2bf(ao[td][r]);
        }
    }
#undef LOAD_K
#undef LOAD_P
#undef LOAD_V
#undef STORE_K
#undef STORE_P
#undef STORE_V
}

__global__ __launch_bounds__(256)
void ln_kernel(const float* __restrict__ X, const float* __restrict__ g,
               const float* __restrict__ bta, float* __restrict__ out)
{
    const int row = blockIdx.x;
    const int tid = threadIdx.x;
    float2 x = *(const float2*)&X[row * 512 + tid * 2];
    float s  = x.x + x.y;
    float s2 = x.x * x.x + x.y * x.y;
    for (int off = 32; off; off >>= 1) {
        s  += __shfl_down(s, off, 64);
        s2 += __shfl_down(s2, off, 64);
    }
    __shared__ float rs[4], rs2[4];
    __shared__ float mu_s, rstd_s;
    int wave = tid >> 6, lane = tid & 63;
    if (lane == 0) { rs[wave] = s; rs2[wave] = s2; }
    __syncthreads();
    if (tid == 0) {
        float S1 = rs[0] + rs[1] + rs[2] + rs[3];
        float S2 = rs2[0] + rs2[1] + rs2[2] + rs2[3];
        float mu = S1 * (1.0f / 512.0f);
        float var = S2 * (1.0f / 512.0f) - mu * mu;
        mu_s = mu;
        rstd_s = rsqrtf(var + 1e-6f);
    }
    __syncthreads();
    float mu = mu_s, rstd = rstd_s;
    float2 gv = *(const float2*)&g[tid * 2];
    float2 bv = *(const float2*)&bta[tid * 2];
    float2 o;
    o.x = (x.x - mu) * rstd * gv.x + bv.x;
    o.y = (x.y - mu) * rstd * gv.y + bv.y;
    *(float2*)&out[row * 512 + tid * 2] = o;
}

extern "C" void kernel_launch(void* const* d_in, const int* in_sizes, int n_in,
                              void* d_out, int out_size, void* d_ws, size_t ws_size,
                              hipStream_t stream)
{
    const float* q       = (const float*)d_in[0];
    const float* k       = (const float*)d_in[1];
    const float* v       = (const float*)d_in[2];
    const float* pos_mat = (const float*)d_in[3];
    const float* w_qs    = (const float*)d_in[4];
    const float* w_ks    = (const float*)d_in[5];
    const float* w_vs    = (const float*)d_in[6];
    const float* w_fc    = (const float*)d_in[7];
    const float* rp_w1   = (const float*)d_in[8];
    const float* rp_b1   = (const float*)d_in[9];
    const float* rp_w2   = (const float*)d_in[10];
    const float* rp_b2   = (const float*)d_in[11];
    const float* ln_g    = (const float*)d_in[12];
    const float* ln_b    = (const float*)d_in[13];

    char* wsb = (char*)d_ws;
    float*    wc  = (float*)d_ws;
    ushort_t* XQ  = (ushort_t*)(wsb + XQ_OFF);
    ushort_t* XK  = (ushort_t*)(wsb + XK_OFF);
    ushort_t* XV  = (ushort_t*)(wsb + XV_OFF);
    ushort_t* WQ  = (ushort_t*)(wsb + WQ_OFF);
    ushort_t* WK  = (ushort_t*)(wsb + WK_OFF);
    ushort_t* WV  = (ushort_t*)(wsb + WV_OFF);
    ushort_t* WF  = (ushort_t*)(wsb + WF_OFF);
    ushort_t* Qbf = (ushort_t*)(wsb + QBF_OFF);
    ushort_t* Kbf = (ushort_t*)(wsb + KBF_OFF);
    ushort_t* Vt  = (ushort_t*)(wsb + VT_OFF);
    float*    O2  = (float*)(wsb + O2_OFF);
    ushort_t* Obf = (ushort_t*)(wsb + OBF_OFF);
    unsigned* Pbf = (unsigned*)(wsb + POSBF_OFF);

    float* out  = (float*)d_out;       // final (B,S,512)
    float* attn = out + 2097152;       // (B,H,S,S) probs

    prep_kernel<<<dim3(1), dim3(64), 0, stream>>>(rp_w1, rp_b1, rp_w2, rp_b2, wc);

    cvt3_kernel<<<dim3(2048, 3), 256, 0, stream>>>(q, k, v, XQ, XK, XV);
    cvt4_kernel<<<dim3(256, 4), 256, 0, stream>>>(w_qs, w_ks, w_vs, w_fc, WQ, WK, WV, WF);

    dim3 gp(8, 64);
    mfma_gemm<0><<<gp, 256, 0, stream>>>(XQ, WQ, Qbf, nullptr, nullptr, nullptr);
    // XQ dead now; pack pos into its region (read by fused_attn, overwritten by O2 later)
    poscvt_kernel<<<dim3(1024), 256, 0, stream>>>(pos_mat, Pbf);
    mfma_gemm<1><<<gp, 256, 0, stream>>>(XK, WK, Kbf, nullptr, wc, nullptr);
    mfma_gemm<2><<<gp, 256, 0, stream>>>(XV, WV, Vt, nullptr, nullptr, nullptr);

    fused_attn<<<dim3(32, 16), 256, 0, stream>>>(Qbf, Kbf, Pbf, Vt, attn, Obf);

    mfma_gemm<3><<<gp, 256, 0, stream>>>(Obf, WF, nullptr, O2, nullptr, q);
    ln_kernel<<<dim3(4096), 256, 0, stream>>>(O2, ln_g, ln_b, out);
}

// Round 6
// 296.480 us; speedup vs baseline: 1.3949x; 1.3949x over previous
//
#include <hip/hip_runtime.h>
#include <math.h>

// Problem constants
#define NB   4
#define SEQ  1024
#define DMOD 512
#define NHD  8
#define DK   64

typedef unsigned short ushort_t;
typedef __attribute__((ext_vector_type(8))) short bf16x8;
typedef __attribute__((ext_vector_type(4))) float f32x4;

// ---------------- workspace layout (bytes) ----------------
// (offsets kept from prior rounds; XQ/XK/XV regions now mostly repurposed)
#define XQ_OFF   1024
#define XK_OFF   (XQ_OFF + 4194304)
#define XV_OFF   (XK_OFF + 4194304)
#define WQ_OFF   (XV_OFF + 4194304)
#define WK_OFF   (WQ_OFF + 524288)
#define WV_OFF   (WK_OFF + 524288)
#define WF_OFF   (WV_OFF + 524288)
#define QBF_OFF  (WF_OFF + 524288)
#define KBF_OFF  (QBF_OFF + 4194304)
#define VT_OFF   (KBF_OFF + 12582912)
// aliases (stream-ordered safe):
#define POSBF_OFF XQ_OFF  // 4MB packed-bf16 pos; written by poscvt (early),
                          // read by fused_attn, overwritten by O2 afterwards.
#define O2_OFF   XQ_OFF   // fp32 8MB, written by fc AFTER fused_attn
#define OBF_OFF  XV_OFF   // bf16 4MB, written by fused_attn

__device__ inline ushort_t f2bf(float x) {
    unsigned u = __builtin_bit_cast(unsigned, x);
    unsigned r = (u + 0x7FFFu + ((u >> 16) & 1u)) >> 16;
    return (ushort_t)r;
}
__device__ inline unsigned pk2(float a, float b) {
    return (unsigned)f2bf(a) | ((unsigned)f2bf(b) << 16);
}

__global__ __launch_bounds__(64)
void prep_kernel(const float* __restrict__ rp_w1, const float* __restrict__ rp_b1,
                 const float* __restrict__ rp_w2, const float* __restrict__ rp_b2,
                 float* __restrict__ ws)
{
    int d = threadIdx.x;
    float w0 = 0.f, w1 = 0.f, cc = 0.f;
    for (int j = 0; j < 64; j++) {
        float r2 = rp_w2[d * 64 + j];
        w0 += r2 * rp_w1[j * 2 + 0];
        w1 += r2 * rp_w1[j * 2 + 1];
        cc += r2 * rp_b1[j];
    }
    ws[d] = cc + rp_b2[d];
    ws[64 + 2 * d + 0] = w0;
    ws[64 + 2 * d + 1] = w1;
}

__global__ __launch_bounds__(256)
void cvt4_kernel(const float* __restrict__ s0, const float* __restrict__ s1,
                 const float* __restrict__ s2, const float* __restrict__ s3,
                 ushort_t* __restrict__ d0, ushort_t* __restrict__ d1,
                 ushort_t* __restrict__ d2, ushort_t* __restrict__ d3)
{
    int t = blockIdx.x * 256 + threadIdx.x;
    const float* s = (blockIdx.y == 0) ? s0 : (blockIdx.y == 1) ? s1
                   : (blockIdx.y == 2) ? s2 : s3;
    ushort_t* d = (blockIdx.y == 0) ? d0 : (blockIdx.y == 1) ? d1
                : (blockIdx.y == 2) ? d2 : d3;
    float4 v = *(const float4*)&s[t * 4];
    uint2 o = {pk2(v.x, v.y), pk2(v.z, v.w)};
    *(uint2*)&d[t * 4] = o;
}

// pos (S,S,2) fp32 -> packed bf16 pair per (q,k): u = bf16(ch0) | bf16(ch1)<<16
__global__ __launch_bounds__(256)
void poscvt_kernel(const float* __restrict__ pos, unsigned* __restrict__ posbf)
{
    int t = blockIdx.x * 256 + threadIdx.x;     // 262144 threads, 4 pairs each
    float4 a = *(const float4*)&pos[t * 8];
    float4 b = *(const float4*)&pos[t * 8 + 4];
    uint4 o = {pk2(a.x, a.y), pk2(a.z, a.w), pk2(b.x, b.y), pk2(b.z, b.w)};
    *(uint4*)&posbf[t * 4] = o;
}

#define GP 72

// ---------------------------------------------------------------------------
// Merged Q/K/V projection GEMM (R5): blockIdx.z selects {Q,K,V}. Reads fp32
// activations DIRECTLY (cvt3 pass removed; bf16 conversion happens in the
// staging, same f2bf rounding => numerically identical). 1536 blocks
// (~6/CU vs 2/CU when launched separately) so staging latency is hidden
// by TLP instead of being exposed per-kernel.
// Y[n,o] = sum_m X[n,m]*Wt[o,m]; N=4096, O=512, M=512.
// ---------------------------------------------------------------------------
__global__ __launch_bounds__(256)
void mfma_gemm_qkv(const float* __restrict__ xq, const float* __restrict__ xk,
                   const float* __restrict__ xv,
                   const ushort_t* __restrict__ wq, const ushort_t* __restrict__ wk,
                   const ushort_t* __restrict__ wv,
                   ushort_t* __restrict__ Qbf, ushort_t* __restrict__ Kbf,
                   ushort_t* __restrict__ Vt, const float* __restrict__ wc)
{
    __shared__ ushort_t Xs[64 * GP];
    __shared__ ushort_t Ws[64 * GP];
    const int bz = blockIdx.z;
    const float* X = (bz == 0) ? xq : (bz == 1) ? xk : xv;
    const ushort_t* Wt = (bz == 0) ? wq : (bz == 1) ? wk : wv;
    const int n0 = blockIdx.y * 64;
    const int o0 = blockIdx.x * 64;
    const int tid = threadIdx.x;
    const int wave = tid >> 6, lane = tid & 63;
    const int m16 = lane & 15, g = lane >> 4;

    f32x4 acc[4] = {};
    for (int m0 = 0; m0 < 512; m0 += 64) {
        #pragma unroll
        for (int it = 0; it < 2; it++) {
            int idx = tid + it * 256;
            int row = idx >> 3, c8 = (idx & 7) * 8;
            float4 a = *(const float4*)&X[(n0 + row) * 512 + m0 + c8];
            float4 b = *(const float4*)&X[(n0 + row) * 512 + m0 + c8 + 4];
            uint4 o = {pk2(a.x, a.y), pk2(a.z, a.w), pk2(b.x, b.y), pk2(b.z, b.w)};
            *(uint4*)&Xs[row * GP + c8] = o;
            *(uint4*)&Ws[row * GP + c8] = *(const uint4*)&Wt[(o0 + row) * 512 + m0 + c8];
        }
        __syncthreads();
        #pragma unroll
        for (int kc = 0; kc < 2; kc++) {
            bf16x8 a = *(const bf16x8*)&Xs[(wave * 16 + m16) * GP + kc * 32 + g * 8];
            #pragma unroll
            for (int to = 0; to < 4; to++) {
                bf16x8 b = *(const bf16x8*)&Ws[(to * 16 + m16) * GP + kc * 32 + g * 8];
                acc[to] = __builtin_amdgcn_mfma_f32_16x16x32_bf16(a, b, acc[to], 0, 0, 0);
            }
        }
        __syncthreads();
    }
    #pragma unroll
    for (int to = 0; to < 4; to++) {
        int o = o0 + to * 16 + m16;
        #pragma unroll
        for (int r = 0; r < 4; r++) {
            int n = n0 + wave * 16 + g * 4 + r;
            float a = acc[to][r];
            int b = n >> 10, s = n & 1023, h = o >> 6, d = o & 63;
            if (bz == 0) {
                Qbf[(((b * NHD + h) << 10) + s) * 64 + d] = f2bf(a);
            } else if (bz == 1) {
                int base = ((((b * NHD + h) << 10) + s) * 192) + d;
                Kbf[base]       = f2bf(a * wc[d]);
                Kbf[base + 64]  = f2bf(a * wc[64 + 2 * d + 0]);
                Kbf[base + 128] = f2bf(a * wc[64 + 2 * d + 1]);
            } else {
                Vt[((b * NHD + h) * 64 + d) * 1024 + s] = f2bf(a);
            }
        }
    }
}

// Output-projection GEMM (bf16 X, fp32 out + residual). N=4096, O=512, M=512.
__global__ __launch_bounds__(256)
void mfma_gemm_fc(const ushort_t* __restrict__ X, const ushort_t* __restrict__ Wt,
                  float* __restrict__ ofp, const float* __restrict__ resid)
{
    __shared__ ushort_t Xs[64 * GP];
    __shared__ ushort_t Ws[64 * GP];
    const int n0 = blockIdx.y * 64;
    const int o0 = blockIdx.x * 64;
    const int tid = threadIdx.x;
    const int wave = tid >> 6, lane = tid & 63;
    const int m16 = lane & 15, g = lane >> 4;

    f32x4 acc[4] = {};
    for (int m0 = 0; m0 < 512; m0 += 64) {
        #pragma unroll
        for (int it = 0; it < 2; it++) {
            int idx = tid + it * 256;
            int row = idx >> 3, c8 = (idx & 7) * 8;
            *(uint4*)&Xs[row * GP + c8] = *(const uint4*)&X[(n0 + row) * 512 + m0 + c8];
            *(uint4*)&Ws[row * GP + c8] = *(const uint4*)&Wt[(o0 + row) * 512 + m0 + c8];
        }
        __syncthreads();
        #pragma unroll
        for (int kc = 0; kc < 2; kc++) {
            bf16x8 a = *(const bf16x8*)&Xs[(wave * 16 + m16) * GP + kc * 32 + g * 8];
            #pragma unroll
            for (int to = 0; to < 4; to++) {
                bf16x8 b = *(const bf16x8*)&Ws[(to * 16 + m16) * GP + kc * 32 + g * 8];
                acc[to] = __builtin_amdgcn_mfma_f32_16x16x32_bf16(a, b, acc[to], 0, 0, 0);
            }
        }
        __syncthreads();
    }
    #pragma unroll
    for (int to = 0; to < 4; to++) {
        int o = o0 + to * 16 + m16;
        #pragma unroll
        for (int r = 0; r < 4; r++) {
            int n = n0 + wave * 16 + g * 4 + r;
            ofp[n * 512 + o] = acc[to][r] + resid[n * 512 + o];
        }
    }
}

// ---------------------------------------------------------------------------
// Fused score + softmax + PV — EXACT R3 version (89.4 µs measured), reverted
// after R4's reg-staging experiment spilled to scratch/LDS (WRITE_SIZE 135->
// 440MB, LDS +16KB = preg promoted, kreg to scratch). Ledger:
//   R1: static-max softmax + __expf + Q-in-regs (exposed pos-load latency)
//   R3: pos packed bf16 + staged via LDS coalesced  -> 231 -> 89.4 µs
//   R4: reg-array prefetch -> compiler spill -> 201 µs (REVERTED)
// ---------------------------------------------------------------------------
#define QPITCH 72
#define KPLANE (64 * QPITCH + 8)
#define POSP 68   // uints per pos row: 64 + 4 pad (row pitch 272B, 16B-aligned)
__global__ __launch_bounds__(256)
void fused_attn(const ushort_t* __restrict__ Qbf, const ushort_t* __restrict__ Kbf,
                const unsigned* __restrict__ posu, const ushort_t* __restrict__ Vt,
                float* __restrict__ attn, ushort_t* __restrict__ Obf)
{
    __shared__ ushort_t Ks[3 * KPLANE];      // 27696 B
    __shared__ ushort_t Vs[64 * QPITCH];     //  9216 B
    __shared__ ushort_t Ps[64 * QPITCH];     //  9216 B
    __shared__ unsigned PosS[64 * POSP];     // 17408 B   (total 63536 B)
    const int bh = blockIdx.x;
    const int q0 = blockIdx.y * 64;
    const int tid = threadIdx.x;
    const int wave = tid >> 6, lane = tid & 63;
    const int m16 = lane & 15, g = lane >> 4;

    // Q fragment directly global -> registers (one-time, 16B x2 per thread)
    const ushort_t* qrow = &Qbf[((bh << 10) + q0 + wave * 16 + m16) * 64];
    bf16x8 qf0 = *(const bf16x8*)&qrow[g * 8];
    bf16x8 qf1 = *(const bf16x8*)&qrow[32 + g * 8];

    float l[4] = {0.f, 0.f, 0.f, 0.f};

    // ---------------- pass 1: denominator sum (static max = 0) ----------------
    for (int k0 = 0; k0 < 1024; k0 += 64) {
        #pragma unroll
        for (int it = 0; it < 6; it++) {
            int idx = tid + it * 256;
            int row = idx / 24, c = idx % 24;
            int j = c >> 3, d8 = (c & 7) * 8;
            *(uint4*)&Ks[j * KPLANE + row * QPITCH + d8] =
                *(const uint4*)&Kbf[((bh << 10) + k0 + row) * 192 + c * 8];
        }
        #pragma unroll
        for (int it = 0; it < 4; it++) {
            int idx = tid + it * 256;              // 0..1023
            int row = idx >> 4, c4 = (idx & 15) * 4;
            *(uint4*)&PosS[row * POSP + c4] =
                *(const uint4*)&posu[(q0 + row) * 1024 + k0 + c4];
        }
        __syncthreads();

        f32x4 sc[4][3] = {};
        #pragma unroll
        for (int kc = 0; kc < 2; kc++) {
            bf16x8 af = kc ? qf1 : qf0;
            #pragma unroll
            for (int tk = 0; tk < 4; tk++)
                #pragma unroll
                for (int j = 0; j < 3; j++) {
                    bf16x8 bfv = *(const bf16x8*)&Ks[j * KPLANE + (tk * 16 + m16) * QPITCH + kc * 32 + g * 8];
                    sc[tk][j] = __builtin_amdgcn_mfma_f32_16x16x32_bf16(af, bfv, sc[tk][j], 0, 0, 0);
                }
        }

        #pragma unroll
        for (int r = 0; r < 4; r++) {
            #pragma unroll
            for (int tk = 0; tk < 4; tk++) {
                unsigned pu = PosS[(wave * 16 + g * 4 + r) * POSP + tk * 16 + m16];
                float p0 = __builtin_bit_cast(float, pu << 16);
                float p1 = __builtin_bit_cast(float, pu & 0xFFFF0000u);
                float s = (sc[tk][0][r] + p0 * sc[tk][1][r] + p1 * sc[tk][2][r]) * 0.125f;
                l[r] += __expf(s);
            }
        }
        __syncthreads();
    }
    // single cross-lane reduce (16-lane groups share the same q rows)
    float inv_l[4];
    #pragma unroll
    for (int r = 0; r < 4; r++) {
        float s = l[r];
        #pragma unroll
        for (int msk = 1; msk < 16; msk <<= 1) s += __shfl_xor(s, msk, 64);
        inv_l[r] = 1.0f / s;
    }

    // ---------------- pass 2: probs write + PV ----------------
    f32x4 ao[4] = {};
    for (int k0 = 0; k0 < 1024; k0 += 64) {
        #pragma unroll
        for (int it = 0; it < 6; it++) {
            int idx = tid + it * 256;
            int row = idx / 24, c = idx % 24;
            int j = c >> 3, d8 = (c & 7) * 8;
            *(uint4*)&Ks[j * KPLANE + row * QPITCH + d8] =
                *(const uint4*)&Kbf[((bh << 10) + k0 + row) * 192 + c * 8];
        }
        #pragma unroll
        for (int it = 0; it < 2; it++) {
            int idx = tid + it * 256;
            int row = idx >> 3, c8 = (idx & 7) * 8;
            *(uint4*)&Vs[row * QPITCH + c8] = *(const uint4*)&Vt[(bh * 64 + row) * 1024 + k0 + c8];
        }
        #pragma unroll
        for (int it = 0; it < 4; it++) {
            int idx = tid + it * 256;
            int row = idx >> 4, c4 = (idx & 15) * 4;
            *(uint4*)&PosS[row * POSP + c4] =
                *(const uint4*)&posu[(q0 + row) * 1024 + k0 + c4];
        }
        __syncthreads();

        f32x4 sc[4][3] = {};
        #pragma unroll
        for (int kc = 0; kc < 2; kc++) {
            bf16x8 af = kc ? qf1 : qf0;
            #pragma unroll
            for (int tk = 0; tk < 4; tk++)
                #pragma unroll
                for (int j = 0; j < 3; j++) {
                    bf16x8 bfv = *(const bf16x8*)&Ks[j * KPLANE + (tk * 16 + m16) * QPITCH + kc * 32 + g * 8];
                    sc[tk][j] = __builtin_amdgcn_mfma_f32_16x16x32_bf16(af, bfv, sc[tk][j], 0, 0, 0);
                }
        }

        #pragma unroll
        for (int r = 0; r < 4; r++) {
            int q = q0 + wave * 16 + g * 4 + r;
            #pragma unroll
            for (int tk = 0; tk < 4; tk++) {
                unsigned pu = PosS[(wave * 16 + g * 4 + r) * POSP + tk * 16 + m16];
                float p0 = __builtin_bit_cast(float, pu << 16);
                float p1 = __builtin_bit_cast(float, pu & 0xFFFF0000u);
                float s = (sc[tk][0][r] + p0 * sc[tk][1][r] + p1 * sc[tk][2][r]) * 0.125f;
                float p = __expf(s) * inv_l[r];
                attn[((bh << 10) + q) * 1024 + k0 + tk * 16 + m16] = p;
                Ps[(wave * 16 + g * 4 + r) * QPITCH + tk * 16 + m16] = f2bf(p);
            }
        }
        __syncthreads();

        #pragma unroll
        for (int kc = 0; kc < 2; kc++) {
            bf16x8 a = *(const bf16x8*)&Ps[(wave * 16 + m16) * QPITCH + kc * 32 + g * 8];
            #pragma unroll
            for (int td = 0; td < 4; td++) {
                bf16x8 b = *(const bf16x8*)&Vs[(td * 16 + m16) * QPITCH + kc * 32 + g * 8];
                ao[td] = __builtin_amdgcn_mfma_f32_16x16x32_bf16(a, b, ao[td], 0, 0, 0);
            }
        }
        __syncthreads();
    }

    const int b = bh >> 3, h = bh & 7;
    #pragma unroll
    for (int td = 0; td < 4; td++) {
        int d = td * 16 + m16;
        #pragma unroll
        for (int r = 0; r < 4; r++) {
            int q = q0 + wave * 16 + g * 4 + r;
            Obf[((b << 10) + q) * 512 + h * 64 + d] = f2bf(ao[td][r]);
        }
    }
}

__global__ __launch_bounds__(256)
void ln_kernel(const float* __restrict__ X, const float* __restrict__ g,
               const float* __restrict__ bta, float* __restrict__ out)
{
    const int row = blockIdx.x;
    const int tid = threadIdx.x;
    float2 x = *(const float2*)&X[row * 512 + tid * 2];
    float s  = x.x + x.y;
    float s2 = x.x * x.x + x.y * x.y;
    for (int off = 32; off; off >>= 1) {
        s  += __shfl_down(s, off, 64);
        s2 += __shfl_down(s2, off, 64);
    }
    __shared__ float rs[4], rs2[4];
    __shared__ float mu_s, rstd_s;
    int wave = tid >> 6, lane = tid & 63;
    if (lane == 0) { rs[wave] = s; rs2[wave] = s2; }
    __syncthreads();
    if (tid == 0) {
        float S1 = rs[0] + rs[1] + rs[2] + rs[3];
        float S2 = rs2[0] + rs2[1] + rs2[2] + rs2[3];
        float mu = S1 * (1.0f / 512.0f);
        float var = S2 * (1.0f / 512.0f) - mu * mu;
        mu_s = mu;
        rstd_s = rsqrtf(var + 1e-6f);
    }
    __syncthreads();
    float mu = mu_s, rstd = rstd_s;
    float2 gv = *(const float2*)&g[tid * 2];
    float2 bv = *(const float2*)&bta[tid * 2];
    float2 o;
    o.x = (x.x - mu) * rstd * gv.x + bv.x;
    o.y = (x.y - mu) * rstd * gv.y + bv.y;
    *(float2*)&out[row * 512 + tid * 2] = o;
}

extern "C" void kernel_launch(void* const* d_in, const int* in_sizes, int n_in,
                              void* d_out, int out_size, void* d_ws, size_t ws_size,
                              hipStream_t stream)
{
    const float* q       = (const float*)d_in[0];
    const float* k       = (const float*)d_in[1];
    const float* v       = (const float*)d_in[2];
    const float* pos_mat = (const float*)d_in[3];
    const float* w_qs    = (const float*)d_in[4];
    const float* w_ks    = (const float*)d_in[5];
    const float* w_vs    = (const float*)d_in[6];
    const float* w_fc    = (const float*)d_in[7];
    const float* rp_w1   = (const float*)d_in[8];
    const float* rp_b1   = (const float*)d_in[9];
    const float* rp_w2   = (const float*)d_in[10];
    const float* rp_b2   = (const float*)d_in[11];
    const float* ln_g    = (const float*)d_in[12];
    const float* ln_b    = (const float*)d_in[13];

    char* wsb = (char*)d_ws;
    float*    wc  = (float*)d_ws;
    ushort_t* WQ  = (ushort_t*)(wsb + WQ_OFF);
    ushort_t* WK  = (ushort_t*)(wsb + WK_OFF);
    ushort_t* WV  = (ushort_t*)(wsb + WV_OFF);
    ushort_t* WF  = (ushort_t*)(wsb + WF_OFF);
    ushort_t* Qbf = (ushort_t*)(wsb + QBF_OFF);
    ushort_t* Kbf = (ushort_t*)(wsb + KBF_OFF);
    ushort_t* Vt  = (ushort_t*)(wsb + VT_OFF);
    float*    O2  = (float*)(wsb + O2_OFF);
    ushort_t* Obf = (ushort_t*)(wsb + OBF_OFF);
    unsigned* Pbf = (unsigned*)(wsb + POSBF_OFF);

    float* out  = (float*)d_out;       // final (B,S,512)
    float* attn = out + 2097152;       // (B,H,S,S) probs

    prep_kernel<<<dim3(1), dim3(64), 0, stream>>>(rp_w1, rp_b1, rp_w2, rp_b2, wc);
    poscvt_kernel<<<dim3(1024), 256, 0, stream>>>(pos_mat, Pbf);
    cvt4_kernel<<<dim3(256, 4), 256, 0, stream>>>(w_qs, w_ks, w_vs, w_fc, WQ, WK, WV, WF);

    // merged Q/K/V projections, fp32 inputs read directly (cvt3 removed)
    mfma_gemm_qkv<<<dim3(8, 64, 3), 256, 0, stream>>>(q, k, v, WQ, WK, WV,
                                                      Qbf, Kbf, Vt, wc);

    fused_attn<<<dim3(32, 16), 256, 0, stream>>>(Qbf, Kbf, Pbf, Vt, attn, Obf);

    mfma_gemm_fc<<<dim3(8, 64), 256, 0, stream>>>(Obf, WF, O2, q);
    ln_kernel<<<dim3(4096), 256, 0, stream>>>(O2, ln_g, ln_b, out);
}